// Round 1
// 220.574 us; speedup vs baseline: 1.5188x; 1.5188x over previous
//
#include <hip/hip_runtime.h>
#include <hip/hip_bf16.h>

#define NB   32
#define CIN  128
#define HH   56
#define WW   56
#define COUT 256
#define HW   3136   // 56*56
#define NCHUNK 576  // weight chunks per (b): 2 mtile * 288

typedef __bf16 bf16x8 __attribute__((ext_vector_type(8)));
typedef float floatx4 __attribute__((ext_vector_type(4)));

// ---------------- 1) router: reduce GAP partials (49 hw-blocks) + MLP + softmax(logits/30) ----------------
// gpart[b][hwb][ch]  (32 x 49 x 128), written by xpose without atomics
__global__ void router_kernel(const float* __restrict__ gpart,
                              const float* __restrict__ w1, const float* __restrict__ b1,
                              const float* __restrict__ w2, const float* __restrict__ b2,
                              float* __restrict__ routing) {
    int b = blockIdx.x, ch = threadIdx.x;          // 32 blocks x 128 threads
    __shared__ float gs[CIN];
    __shared__ float hs[16];
    float s = 0.f;
    for (int hwb = 0; hwb < 49; ++hwb)
        s += gpart[((size_t)b * 49 + hwb) * CIN + ch];
    gs[ch] = s * (1.0f / HW);
    __syncthreads();
    if (ch < 16) {
        float a = 0.f;
        #pragma unroll
        for (int i = 0; i < CIN; ++i) a += gs[i] * w1[ch * CIN + i];
        hs[ch] = fmaxf(a + b1[ch], 0.f);
    }
    __syncthreads();
    if (ch == 0) {
        float lg[4], mx = -1e30f;
        #pragma unroll
        for (int e = 0; e < 4; ++e) {
            float a = b2[e];
            #pragma unroll
            for (int r = 0; r < 16; ++r) a += hs[r] * w2[e * 16 + r];
            lg[e] = a * (1.0f / 30.0f);
            mx = fmaxf(mx, lg[e]);
        }
        float den = 0.f, ex[4];
        #pragma unroll
        for (int e = 0; e < 4; ++e) { ex[e] = expf(lg[e] - mx); den += ex[e]; }
        #pragma unroll
        for (int e = 0; e < 4; ++e) routing[b * 4 + e] = ex[e] / den;
    }
}

// ---------------- 2a) swizzle expert weights into MFMA A-fragment chunk order (coalesced) ----------------
// convT[e][c][lane] 16B chunks; c = mtile*288 + p*32 + cc*16 + ks*8 + mt*2 + wm
// block = (e, mtile, wm, mt): owns 16 rows (col 0..15); coalesced float4 reads -> LDS -> swizzled gather
__global__ void wswz_kernel(const float* __restrict__ convs,
                            __hip_bfloat16* __restrict__ convT) {
    int blk = blockIdx.x;                           // 64 blocks
    int mt = blk & 3, wm = (blk >> 2) & 1, mtile = (blk >> 3) & 1, e = blk >> 4;
    int row0 = mtile * 128 + wm * 64 + mt * 16;
    __shared__ float tile[16][585];                 // 576 + 9 pad (2-way-free gather banks)
    const float* src = convs + (size_t)(e * COUT + row0) * (CIN * 9);
    for (int cc = 0; cc < 2; ++cc) {
        if (cc) __syncthreads();                    // protect tile reuse
        // load half the k-range of 16 rows: 16 x 576 floats, coalesced float4
        for (int i = threadIdx.x; i < 2304; i += 256) {
            int r = i / 144, o = i - r * 144;       // 144 float4 per half-row
            float4 v = *(const float4*)(src + (size_t)r * 1152 + cc * 576 + o * 4);
            tile[r][o * 4 + 0] = v.x; tile[r][o * 4 + 1] = v.y;
            tile[r][o * 4 + 2] = v.z; tile[r][o * 4 + 3] = v.w;
        }
        __syncthreads();
        // 18 slots (p x ks) x 64 lanes for this cc
        for (int i = threadIdx.x; i < 1152; i += 256) {
            int slot = i >> 6, lane = i & 63;
            int ks = slot & 1, p = slot >> 1;
            int col = lane & 15, quad = lane >> 4;
            int kl = ks * 32 + quad * 8;            // k local to cc-half
            int c = mtile * 288 + p * 32 + cc * 16 + ks * 8 + mt * 2 + wm;
            __hip_bfloat16 tmp[8];
            #pragma unroll
            for (int j = 0; j < 8; ++j)
                tmp[j] = __float2bfloat16(tile[col][(kl + j) * 9 + p]);
            *(uint4*)(convT + ((size_t)(e * NCHUNK + c) * 64 + lane) * 8) = *(uint4*)tmp;
        }
    }
}

// ---------------- 2b) mix: wmix[b][c][lane] = sum_e r[b][e] * convT[e][c][lane] ----------------
__global__ void mix_kernel(const __hip_bfloat16* __restrict__ convT,
                           const float* __restrict__ routing,
                           __hip_bfloat16* __restrict__ wmix) {
    int t = blockIdx.x * 256 + threadIdx.x;     // (b*576 + c)*64 + lane
    const int PER_B = NCHUNK * 64;              // 36864 chunk-lanes per b
    int b  = t / PER_B;
    float r0 = routing[b * 4 + 0], r1 = routing[b * 4 + 1];
    float r2 = routing[b * 4 + 2], r3 = routing[b * 4 + 3];
    int cl = t - b * PER_B;
    const int ES = PER_B * 8;                   // elems per expert... (per-b slice)
    (void)cl;
    const int EST = 4 * NCHUNK * 64 * 8 / 4;    // silence unused warnings path
    (void)EST;
    int clane = t - b * PER_B;
    const int ESTRIDE = NCHUNK * 64 * 8;        // wait: convT is per-expert, full 576 chunks
    bf16x8 w0 = *(const bf16x8*)(convT + (size_t)clane * 8);
    bf16x8 w1 = *(const bf16x8*)(convT + (size_t)clane * 8 + ESTRIDE);
    bf16x8 w2 = *(const bf16x8*)(convT + (size_t)clane * 8 + 2 * (size_t)ESTRIDE);
    bf16x8 w3 = *(const bf16x8*)(convT + (size_t)clane * 8 + 3 * (size_t)ESTRIDE);
    __hip_bfloat16 o[8];
    #pragma unroll
    for (int j = 0; j < 8; ++j) {
        float s = r0 * (float)w0[j] + r1 * (float)w1[j]
                + r2 * (float)w2[j] + r3 * (float)w3[j];
        o[j] = __float2bfloat16(s);
    }
    *(uint4*)(wmix + (size_t)t * 8) = *(uint4*)o;
}

// ---------------- 3) x: NCHW fp32 -> NHWC bf16, fused GAP partials (NO atomics) ----------------
__global__ void xpose_kernel(const float* __restrict__ x, __hip_bfloat16* __restrict__ xT,
                             float* __restrict__ gpart) {
    int hw0 = blockIdx.x * 64, i0 = blockIdx.y * 64, b = blockIdx.z;
    __shared__ float tile[64][65];
    __shared__ float red[64][4];
    const float* xp = x + ((size_t)b * CIN + i0) * HW + hw0;
    for (int t = threadIdx.x; t < 1024; t += 256) {      // float4 loads
        int ir = t >> 4, c4 = t & 15;
        float4 v = *(const float4*)(xp + (size_t)ir * HW + c4 * 4);
        tile[ir][c4 * 4 + 0] = v.x; tile[ir][c4 * 4 + 1] = v.y;
        tile[ir][c4 * 4 + 2] = v.z; tile[ir][c4 * 4 + 3] = v.w;
    }
    __syncthreads();
    __hip_bfloat16* op = xT + ((size_t)b * HW + hw0) * CIN + i0;
    for (int t = threadIdx.x; t < 512; t += 256) {
        int pp = t >> 3, seg = t & 7;
        __hip_bfloat16 tmp[8];
        #pragma unroll
        for (int j = 0; j < 8; ++j) tmp[j] = __float2bfloat16(tile[seg * 8 + j][pp]);
        *(uint4*)(op + (size_t)pp * CIN + seg * 8) = *(uint4*)tmp;
    }
    int ch = threadIdx.x & 63, grp = threadIdx.x >> 6;
    float s = 0.f;
    #pragma unroll
    for (int k = 0; k < 16; ++k) s += tile[ch][grp * 16 + k];
    red[ch][grp] = s;
    __syncthreads();
    if (threadIdx.x < 64) {
        float t4 = red[threadIdx.x][0] + red[threadIdx.x][1]
                 + red[threadIdx.x][2] + red[threadIdx.x][3];
        gpart[((size_t)b * 49 + blockIdx.x) * CIN + i0 + threadIdx.x] = t4;
    }
}

// ---------------- 4) dynamic conv: 9 shifted MFMA GEMMs, XCD-swizzled, deep prefetch ----------------
#define XSTRIDE 136   // 128 ch + 8 pad elems (16B-aligned rows, conflict-free reads)
__global__ __launch_bounds__(256, 2)
void conv_mfma(const __hip_bfloat16* __restrict__ xT,
               const __hip_bfloat16* __restrict__ wmix,
               float* __restrict__ out) {
    __shared__ __align__(16) __hip_bfloat16 xs[180 * XSTRIDE];   // 48.96 KB

    // XCD-aware bijective swizzle: 1792 % 8 == 0. XCD k owns wg [224k, 224k+224)
    // = 4 contiguous b's -> wmix panel + xT stay L2-resident per XCD.
    int lin = blockIdx.x;
    int wg  = (lin & 7) * 224 + (lin >> 3);
    int b   = wg / 56;
    int rr  = wg - b * 56;
    int mtile = rr / 28;
    int tile  = rr - mtile * 28;

    const int yt = tile >> 2, xt = tile & 3;
    const int y0 = yt * 8, x0 = xt * 16;
    const int tid = threadIdx.x;
    const int lane = tid & 63, wave = tid >> 6;
    const int wm = wave & 1, wn = wave >> 1;
    const int col = lane & 15, quad = lane >> 4;

    const __hip_bfloat16* xb = xT + (size_t)b * HW * CIN;
    const __hip_bfloat16* wptr = wmix +
        ((size_t)(b * NCHUNK + mtile * 288 + wm)) * 512 + lane * 8;

    // ---- stage full x halo tile (180 px x 128 ch) once ----
    #pragma unroll
    for (int j = 0; j < 12; ++j) {
        int tt = tid + j * 256;
        if (tt < 2880) {                       // 180 px * 16 segs
            int pix = tt >> 4, seg = tt & 15;
            int py = pix / 18, px = pix - py * 18;
            int gy = y0 - 1 + py, gx = x0 - 1 + px;
            uint4 v = {0u, 0u, 0u, 0u};
            if ((unsigned)gy < 56u && (unsigned)gx < 56u)
                v = *(const uint4*)(xb + ((size_t)(gy * 56 + gx) * CIN + seg * 8));
            *(uint4*)(&xs[pix * XSTRIDE + seg * 8]) = v;
        }
    }

    floatx4 acc[4][4];
    #pragma unroll
    for (int mt = 0; mt < 4; ++mt)
        #pragma unroll
        for (int nt = 0; nt < 4; ++nt)
            acc[mt][nt] = (floatx4){0.f, 0.f, 0.f, 0.f};

    bf16x8 af[4][4];   // rotating weight prefetch (3 steps ahead)
    bf16x8 bfr[3][4];  // rotating x fragments (2 steps ahead)

    auto loadaf = [&](int s, bf16x8* dst) {
        const int cc = s / 18, pp = (s % 18) >> 1, ks = s & 1;
        #pragma unroll
        for (int mt = 0; mt < 4; ++mt)
            dst[mt] = *(const bf16x8*)(wptr +
                (size_t)(pp * 32 + cc * 16 + ks * 8 + mt * 2) * 512);
    };
    auto loadbfr = [&](int s, bf16x8* dst) {
        const int cc = s / 18, pp = (s % 18) >> 1, ks = s & 1;
        const int ky = pp / 3, kx = pp - ky * 3;
        #pragma unroll
        for (int nt = 0; nt < 4; ++nt) {
            int pyy = wn * 4 + nt + ky;       // LDS row 0 = y0-1
            int pxx = col + kx;
            dst[nt] = *(const bf16x8*)(&xs[(pyy * 18 + pxx) * XSTRIDE +
                                           cc * 64 + ks * 32 + quad * 8]);
        }
    };

    loadaf(0, af[0]);
    loadaf(1, af[1]);
    loadaf(2, af[2]);
    __syncthreads();                          // xs visible (the only barrier)
    loadbfr(0, bfr[0]);
    loadbfr(1, bfr[1]);

    #pragma unroll
    for (int s = 0; s < 36; ++s) {
        if (s + 3 < 36) loadaf(s + 3, af[(s + 3) & 3]);
        if (s + 2 < 36) loadbfr(s + 2, bfr[(s + 2) % 3]);
        __builtin_amdgcn_s_setprio(1);
        #pragma unroll
        for (int mt = 0; mt < 4; ++mt)
            #pragma unroll
            for (int nt = 0; nt < 4; ++nt)
                acc[mt][nt] = __builtin_amdgcn_mfma_f32_16x16x32_bf16(
                    af[s & 3][mt], bfr[s % 3][nt], acc[mt][nt], 0, 0, 0);
        __builtin_amdgcn_s_setprio(0);
    }

    // epilogue: C/D layout col=lane&15, row=quad*4+reg
    const int x = x0 + col;
    if (x < 56) {
        #pragma unroll
        for (int mt = 0; mt < 4; ++mt) {
            int o = mtile * 128 + wm * 64 + mt * 16 + quad * 4;
            #pragma unroll
            for (int nt = 0; nt < 4; ++nt) {
                int y = y0 + wn * 4 + nt;
                float* op = out + (((size_t)b * COUT + o) * 56 + y) * 56 + x;
                #pragma unroll
                for (int r = 0; r < 4; ++r)
                    op[(size_t)r * HW] = acc[mt][nt][r];
            }
        }
    }
}

extern "C" void kernel_launch(void* const* d_in, const int* in_sizes, int n_in,
                              void* d_out, int out_size, void* d_ws, size_t ws_size,
                              hipStream_t stream) {
    const float* x     = (const float*)d_in[0];
    const float* convs = (const float*)d_in[1];
    const float* w1    = (const float*)d_in[2];
    const float* b1    = (const float*)d_in[3];
    const float* w2    = (const float*)d_in[4];
    const float* b2    = (const float*)d_in[5];
    float* out = (float*)d_out;

    char* ws = (char*)d_ws;
    float* routing       = (float*)(ws + 16384);                        // 512 B
    __hip_bfloat16* xT   = (__hip_bfloat16*)(ws + 16896);               // 25690112 B
    __hip_bfloat16* wmix = (__hip_bfloat16*)(ws + 16896 + 25690112);    // 18874368 B
    __hip_bfloat16* convT= (__hip_bfloat16*)(ws + 16896 + 25690112 + 18874368); // 2359296 B
    // GAP partials alias the wmix region: written by xpose, consumed by router,
    // and only then is wmix produced by mix_kernel (stream-serial => safe).
    float* gpart = (float*)wmix;                                        // 802816 B used

    wswz_kernel  <<<64, 256, 0, stream>>>(convs, convT);
    xpose_kernel <<<dim3(49, 2, NB), 256, 0, stream>>>(x, xT, gpart);
    router_kernel<<<NB, 128, 0, stream>>>(gpart, w1, b1, w2, b2, routing);
    mix_kernel   <<<(NB * NCHUNK * 64) / 256, 256, 0, stream>>>(convT, routing, wmix);
    conv_mfma    <<<1792, 256, 0, stream>>>(xT, wmix, out);
}

// Round 2
// 210.914 us; speedup vs baseline: 1.5884x; 1.0458x over previous
//
#include <hip/hip_runtime.h>
#include <hip/hip_bf16.h>

#define NB   32
#define CIN  128
#define HH   56
#define WW   56
#define COUT 256
#define HW   3136   // 56*56
#define NCHUNK 576  // weight chunks per (b): 2 mtile * 288

typedef __bf16 bf16x8 __attribute__((ext_vector_type(8)));
typedef float floatx4 __attribute__((ext_vector_type(4)));

// ---------------- 1) router: reduce GAP partials (49 hw-blocks) + MLP + softmax(logits/30) ----------------
// gpart[b][hwb][ch]  (32 x 49 x 128), written by xpose without atomics
__global__ void router_kernel(const float* __restrict__ gpart,
                              const float* __restrict__ w1, const float* __restrict__ b1,
                              const float* __restrict__ w2, const float* __restrict__ b2,
                              float* __restrict__ routing) {
    int b = blockIdx.x, ch = threadIdx.x;          // 32 blocks x 128 threads
    __shared__ float gs[CIN];
    __shared__ float hs[16];
    float s = 0.f;
    #pragma unroll 7
    for (int hwb = 0; hwb < 49; ++hwb)
        s += gpart[((size_t)b * 49 + hwb) * CIN + ch];
    gs[ch] = s * (1.0f / HW);
    __syncthreads();
    if (ch < 16) {
        float a = 0.f;
        #pragma unroll
        for (int i = 0; i < CIN; ++i) a += gs[i] * w1[ch * CIN + i];
        hs[ch] = fmaxf(a + b1[ch], 0.f);
    }
    __syncthreads();
    if (ch == 0) {
        float lg[4], mx = -1e30f;
        #pragma unroll
        for (int e = 0; e < 4; ++e) {
            float a = b2[e];
            #pragma unroll
            for (int r = 0; r < 16; ++r) a += hs[r] * w2[e * 16 + r];
            lg[e] = a * (1.0f / 30.0f);
            mx = fmaxf(mx, lg[e]);
        }
        float den = 0.f, ex[4];
        #pragma unroll
        for (int e = 0; e < 4; ++e) { ex[e] = expf(lg[e] - mx); den += ex[e]; }
        #pragma unroll
        for (int e = 0; e < 4; ++e) routing[b * 4 + e] = ex[e] / den;
    }
}

// ---------------- 2) FUSED: x transpose (+GAP partials) AND expert-weight swizzle ----------------
// blocks [0,3136): xpose   NCHW fp32 -> NHWC bf16, gpart partials (no atomics)
// blocks [3136,3392): wswz  convT[e][c][lane], c = mtile*288 + p*32 + cc*16 + ks*8 + mt*2 + wm
__global__ void xpose_wswz(const float* __restrict__ x, __hip_bfloat16* __restrict__ xT,
                           float* __restrict__ gpart,
                           const float* __restrict__ convs, __hip_bfloat16* __restrict__ convT) {
    __shared__ __align__(16) char smem[19008];
    int blk = blockIdx.x;
    if (blk < 3136) {
        // ---- xpose path ----
        int hwb = blk % 49; int rem = blk / 49; int ih = rem & 1; int b = rem >> 1;
        int hw0 = hwb * 64, i0 = ih * 64;
        float (*tile)[65] = (float(*)[65])smem;                 // 16640 B
        float (*red)[4]   = (float(*)[4])(smem + 16640);        // 1024 B
        const float* xp = x + ((size_t)b * CIN + i0) * HW + hw0;
        for (int t = threadIdx.x; t < 1024; t += 256) {         // float4 loads
            int ir = t >> 4, c4 = t & 15;
            float4 v = *(const float4*)(xp + (size_t)ir * HW + c4 * 4);
            tile[ir][c4 * 4 + 0] = v.x; tile[ir][c4 * 4 + 1] = v.y;
            tile[ir][c4 * 4 + 2] = v.z; tile[ir][c4 * 4 + 3] = v.w;
        }
        __syncthreads();
        __hip_bfloat16* op = xT + ((size_t)b * HW + hw0) * CIN + i0;
        for (int t = threadIdx.x; t < 512; t += 256) {
            int pp = t >> 3, seg = t & 7;
            __hip_bfloat16 tmp[8];
            #pragma unroll
            for (int j = 0; j < 8; ++j) tmp[j] = __float2bfloat16(tile[seg * 8 + j][pp]);
            *(uint4*)(op + (size_t)pp * CIN + seg * 8) = *(uint4*)tmp;
        }
        int ch = threadIdx.x & 63, grp = threadIdx.x >> 6;
        float s = 0.f;
        #pragma unroll
        for (int k = 0; k < 16; ++k) s += tile[ch][grp * 16 + k];
        red[ch][grp] = s;
        __syncthreads();
        if (threadIdx.x < 64) {
            float t4 = red[threadIdx.x][0] + red[threadIdx.x][1]
                     + red[threadIdx.x][2] + red[threadIdx.x][3];
            gpart[((size_t)b * 49 + blk % 49) * CIN + i0 + threadIdx.x] = t4;
        }
    } else {
        // ---- wswz path: 256 blocks = (e, mtile, wm, mt, cc, ks) ----
        int b2 = blk - 3136;
        int ks = b2 & 1, cc = (b2 >> 1) & 1, mt = (b2 >> 2) & 3;
        int wm = (b2 >> 4) & 1, mtile = (b2 >> 5) & 1, e = b2 >> 6;
        float (*tl)[297] = (float(*)[297])smem;                 // 16 x 297 x 4 = 19008 B
        int row0 = mtile * 128 + wm * 64 + mt * 16;
        const float* src = convs + (size_t)(e * COUT + row0) * 1152 + (cc * 64 + ks * 32) * 9;
        for (int i = threadIdx.x; i < 1152; i += 256) {         // 16 rows x 72 float4
            int r = i / 72, o = i - r * 72;
            float4 v = *(const float4*)(src + (size_t)r * 1152 + o * 4);
            tl[r][o * 4 + 0] = v.x; tl[r][o * 4 + 1] = v.y;
            tl[r][o * 4 + 2] = v.z; tl[r][o * 4 + 3] = v.w;
        }
        __syncthreads();
        for (int i = threadIdx.x; i < 576; i += 256) {          // 9 p-slots x 64 lanes
            int p = i >> 6, lane = i & 63;
            int col = lane & 15, quad = lane >> 4;
            int c = mtile * 288 + p * 32 + cc * 16 + ks * 8 + mt * 2 + wm;
            __hip_bfloat16 tmp[8];
            #pragma unroll
            for (int j = 0; j < 8; ++j)
                tmp[j] = __float2bfloat16(tl[col][(quad * 8 + j) * 9 + p]);
            *(uint4*)(convT + ((size_t)(e * NCHUNK + c) * 64 + lane) * 8) = *(uint4*)tmp;
        }
    }
}

// ---------------- 3) mix: wmix[b][c][lane] = sum_e r[b][e] * convT[e][c][lane] (32B/thread) ----------------
__global__ void mix_kernel(const __hip_bfloat16* __restrict__ convT,
                           const float* __restrict__ routing,
                           __hip_bfloat16* __restrict__ wmix) {
    int t = blockIdx.x * 256 + threadIdx.x;     // one PAIR of chunk-lanes (32 B)
    const int PER_B = NCHUNK * 32;              // 18432 pairs per b
    int b = t / PER_B;
    int p = t - b * PER_B;                      // pair index within b (== convT pair index)
    float r0 = routing[b * 4 + 0], r1 = routing[b * 4 + 1];
    float r2 = routing[b * 4 + 2], r3 = routing[b * 4 + 3];
    const size_t ES = (size_t)NCHUNK * 64 * 8;  // 294912 elems per expert
    const __hip_bfloat16* sp = convT + (size_t)p * 16;
    __hip_bfloat16 o[16];
    #pragma unroll
    for (int h = 0; h < 2; ++h) {
        bf16x8 w0 = *(const bf16x8*)(sp + h * 8);
        bf16x8 w1 = *(const bf16x8*)(sp + h * 8 + ES);
        bf16x8 w2 = *(const bf16x8*)(sp + h * 8 + 2 * ES);
        bf16x8 w3 = *(const bf16x8*)(sp + h * 8 + 3 * ES);
        #pragma unroll
        for (int j = 0; j < 8; ++j) {
            float v = r0 * (float)w0[j] + r1 * (float)w1[j]
                    + r2 * (float)w2[j] + r3 * (float)w3[j];
            o[h * 8 + j] = __float2bfloat16(v);
        }
    }
    uint4* d = (uint4*)(wmix + (size_t)t * 16);
    d[0] = ((uint4*)o)[0];
    d[1] = ((uint4*)o)[1];
}

// ---------------- 4) dynamic conv: 12 (cc,ks,kx) groups, 6-row bfr reuse across ky ----------------
#define XSTRIDE 136   // 128 ch + 8 pad elems (16B-aligned rows)
__global__ __launch_bounds__(256, 2)
void conv_mfma(const __hip_bfloat16* __restrict__ xT,
               const __hip_bfloat16* __restrict__ wmix,
               float* __restrict__ out) {
    __shared__ __align__(16) __hip_bfloat16 xs[180 * XSTRIDE];   // 48.96 KB

    // XCD-aware bijective swizzle (1792 % 8 == 0): XCD k owns 4 contiguous b's
    int lin = blockIdx.x;
    int wg  = (lin & 7) * 224 + (lin >> 3);
    int b   = wg / 56;
    int rr  = wg - b * 56;
    int mtile = rr / 28;
    int tile  = rr - mtile * 28;

    const int yt = tile >> 2, xt = tile & 3;
    const int y0 = yt * 8, x0 = xt * 16;
    const int tid = threadIdx.x;
    const int lane = tid & 63, wave = tid >> 6;
    const int wm = wave & 1, wn = wave >> 1;
    const int col = lane & 15, quad = lane >> 4;

    const __hip_bfloat16* xb = xT + (size_t)b * HW * CIN;
    const __hip_bfloat16* wptr = wmix +
        ((size_t)(b * NCHUNK + mtile * 288 + wm)) * 512 + lane * 8;

    // ---- stage full x halo tile (180 px x 128 ch) once ----
    #pragma unroll
    for (int j = 0; j < 12; ++j) {
        int tt = tid + j * 256;
        if (tt < 2880) {                       // 180 px * 16 segs
            int pix = tt >> 4, seg = tt & 15;
            int py = pix / 18, px = pix - py * 18;
            int gy = y0 - 1 + py, gx = x0 - 1 + px;
            uint4 v = {0u, 0u, 0u, 0u};
            if ((unsigned)gy < 56u && (unsigned)gx < 56u)
                v = *(const uint4*)(xb + ((size_t)(gy * 56 + gx) * CIN + seg * 8));
            *(uint4*)(&xs[pix * XSTRIDE + seg * 8]) = v;
        }
    }

    floatx4 acc[4][4];
    #pragma unroll
    for (int mt = 0; mt < 4; ++mt)
        #pragma unroll
        for (int nt = 0; nt < 4; ++nt)
            acc[mt][nt] = (floatx4){0.f, 0.f, 0.f, 0.f};

    bf16x8 af[4][4];    // weight fragments: ky-step rotating, prefetch distance 3
    bf16x8 bfr[2][6];   // 6 row-fragments per (cc,ks,kx) group, double-buffered

    // u = g*3 + ky ; g = cc*6 + ks*3 + kx
    auto lda = [&](int u, bf16x8* dst) {
        const int g = u / 3, ky = u - g * 3;
        const int cc = g / 6, r6 = g - cc * 6;
        const int ks = r6 / 3, kx = r6 - ks * 3;
        const int pp = ky * 3 + kx;
        #pragma unroll
        for (int mt = 0; mt < 4; ++mt)
            dst[mt] = *(const bf16x8*)(wptr +
                (size_t)(pp * 32 + cc * 16 + ks * 8 + mt * 2) * 512);
    };
    auto ldb = [&](int g, bf16x8* dst) {
        const int cc = g / 6, r6 = g - cc * 6;
        const int ks = r6 / 3, kx = r6 - ks * 3;
        const int base = cc * 64 + ks * 32 + quad * 8;
        #pragma unroll
        for (int r = 0; r < 6; ++r)
            dst[r] = *(const bf16x8*)(&xs[((wn * 4 + r) * 18 + col + kx) * XSTRIDE + base]);
    };

    lda(0, af[0]); lda(1, af[1]); lda(2, af[2]);
    __syncthreads();                          // xs visible (the only barrier)
    ldb(0, bfr[0]);

    #pragma unroll
    for (int g = 0; g < 12; ++g) {
        if (g + 1 < 12) ldb(g + 1, bfr[(g + 1) & 1]);
        #pragma unroll
        for (int ky = 0; ky < 3; ++ky) {
            const int u = g * 3 + ky;
            if (u + 3 < 36) lda(u + 3, af[(u + 3) & 3]);
            __builtin_amdgcn_s_setprio(1);
            #pragma unroll
            for (int mt = 0; mt < 4; ++mt)
                #pragma unroll
                for (int nt = 0; nt < 4; ++nt)
                    acc[mt][nt] = __builtin_amdgcn_mfma_f32_16x16x32_bf16(
                        af[u & 3][mt], bfr[g & 1][nt + ky], acc[mt][nt], 0, 0, 0);
            __builtin_amdgcn_s_setprio(0);
        }
    }

    // epilogue: C/D layout col=lane&15, row=quad*4+reg
    const int x = x0 + col;
    if (x < 56) {
        #pragma unroll
        for (int mt = 0; mt < 4; ++mt) {
            int o = mtile * 128 + wm * 64 + mt * 16 + quad * 4;
            #pragma unroll
            for (int nt = 0; nt < 4; ++nt) {
                int y = y0 + wn * 4 + nt;
                float* op = out + (((size_t)b * COUT + o) * 56 + y) * 56 + x;
                #pragma unroll
                for (int r = 0; r < 4; ++r)
                    op[(size_t)r * HW] = acc[mt][nt][r];
            }
        }
    }
}

extern "C" void kernel_launch(void* const* d_in, const int* in_sizes, int n_in,
                              void* d_out, int out_size, void* d_ws, size_t ws_size,
                              hipStream_t stream) {
    const float* x     = (const float*)d_in[0];
    const float* convs = (const float*)d_in[1];
    const float* w1    = (const float*)d_in[2];
    const float* b1    = (const float*)d_in[3];
    const float* w2    = (const float*)d_in[4];
    const float* b2    = (const float*)d_in[5];
    float* out = (float*)d_out;

    char* ws = (char*)d_ws;
    float* routing       = (float*)(ws + 16384);                        // 512 B
    __hip_bfloat16* xT   = (__hip_bfloat16*)(ws + 16896);               // 25690112 B
    __hip_bfloat16* wmix = (__hip_bfloat16*)(ws + 16896 + 25690112);    // 18874368 B
    __hip_bfloat16* convT= (__hip_bfloat16*)(ws + 16896 + 25690112 + 18874368); // 2359296 B
    // GAP partials alias the wmix region: written by xpose, consumed by router,
    // and only then is wmix produced by mix_kernel (stream-serial => safe).
    float* gpart = (float*)wmix;                                        // 802816 B used

    xpose_wswz   <<<3392, 256, 0, stream>>>(x, xT, gpart, convs, convT);
    router_kernel<<<NB, 128, 0, stream>>>(gpart, w1, b1, w2, b2, routing);
    mix_kernel   <<<2304, 256, 0, stream>>>(convT, routing, wmix);
    conv_mfma    <<<1792, 256, 0, stream>>>(xT, wmix, out);
}